// Round 3
// baseline (118.726 us; speedup 1.0000x reference)
//
#include <hip/hip_runtime.h>
#include <stdint.h>

#define BS 7
#define HM 50
#define WM 50
#define HH 56
#define WW 56
#define PLANE_IN  (HM * WM)   // 2500
#define PLANE_OUT (HH * WW)   // 3136
#define NPLANES   (64 * 256)  // 16384
#define COUNT_M   51380224.0f // 64*256*56*56 = 49 * 2^20, exact in fp32
#define PPB       8           // planes per block in kernel 2
#define K2_BLOCKS (NPLANES / PPB)  // 2048

// Kernel 1: per-plane 7x7 dilation of the 50x50 seed mask -> 56-row keep
// bitmap (bit w of word h = block_mask[h][w]) + per-plane kept-pixel count
// (plain store; NO global atomics).
__global__ __launch_bounds__(256) void dropblock_dilate(
    const float* __restrict__ mask,
    unsigned long long* __restrict__ bitmap,
    unsigned* __restrict__ counts)
{
    __shared__ unsigned long long rowbits[HM];
    __shared__ unsigned long long rowdil[HM];
    __shared__ unsigned cnt;

    const int tid = threadIdx.x;
    const int p = blockIdx.x;

    if (tid < HM) rowbits[tid] = 0ULL;
    if (tid == 0) cnt = 0;
    __syncthreads();

    // Coalesced float4 read of the 2500-float plane; sparse seeds -> LDS atomicOr.
    const float4* mp = reinterpret_cast<const float4*>(mask + (size_t)p * PLANE_IN);
    for (int j = tid; j < PLANE_IN / 4; j += 256) {  // 2500 = 625*4, no tail
        float4 v = mp[j];
        const int e = 4 * j;
        float vv[4] = {v.x, v.y, v.z, v.w};
#pragma unroll
        for (int k = 0; k < 4; ++k) {
            if (vv[k] != 0.0f) {
                int idx = e + k;
                int r = idx / WM;
                int w = idx - r * WM;
                atomicOr(&rowbits[r], 1ULL << w);
            }
        }
    }
    __syncthreads();

    // Row dilation: bit w of s = OR of mask bits [w-6 .. w].
    if (tid < HM) {
        unsigned long long b = rowbits[tid];
        unsigned long long s = b | (b << 1);  // shifts 0..1
        s |= s << 2;                          // shifts 0..3
        s |= s << 3;                          // shifts 0..6
        rowdil[tid] = s;
    }
    __syncthreads();

    // Column dilation + invert + popcount + store bitmap row.
    unsigned pc = 0;
    if (tid < HH) {
        const int h = tid;
        int lo = h - (BS - 1); if (lo < 0) lo = 0;
        int hi = h;            if (hi > HM - 1) hi = HM - 1;
        unsigned long long d = 0ULL;
        for (int r = lo; r <= hi; ++r) d |= rowdil[r];
        unsigned long long keep = ~d & ((1ULL << 56) - 1ULL);
        bitmap[(size_t)p * HH + h] = keep;
        pc = (unsigned)__popcll(keep);
    }
    if (pc) atomicAdd(&cnt, pc);  // LDS atomic only
    __syncthreads();
    if (tid == 0) counts[p] = cnt;  // plain store
}

// Kernel 2: fused reduce + scale. 2048 blocks x 8 planes each.
// Every block sums counts[16384] itself (64 KB of L2/L3-broadcast reads,
// removes the separate reduce kernel), then streams 8 planes of contiguous
// float4 stores, skipping x loads for all-zero nibbles (~99.4% dropped).
__global__ __launch_bounds__(256) void dropblock_scale(
    const float* __restrict__ x,
    const unsigned long long* __restrict__ bitmap,
    const unsigned* __restrict__ counts,
    float* __restrict__ out)
{
    __shared__ unsigned long long bitsLDS[PPB * HH];  // 448 words
    __shared__ unsigned wsum[4];
    __shared__ float s_scale;

    const int tid = threadIdx.x;

    // Start bitmap loads early (448 u64 per block).
    for (int i = tid; i < PPB * HH; i += 256)
        bitsLDS[i] = bitmap[(size_t)blockIdx.x * (PPB * HH) + i];

    // Block-wide sum of the 16384 per-plane counts (16 uint4 per thread).
    const uint4* cp = reinterpret_cast<const uint4*>(counts);
    unsigned s = 0;
#pragma unroll
    for (int i = 0; i < NPLANES / 4 / 256; ++i) {  // 16
        uint4 v = cp[tid + i * 256];
        s += v.x + v.y + v.z + v.w;
    }
#pragma unroll
    for (int off = 32; off; off >>= 1) s += __shfl_down(s, off, 64);
    if ((tid & 63) == 0) wsum[tid >> 6] = s;
    __syncthreads();
    if (tid == 0) s_scale = COUNT_M / (float)(wsum[0] + wsum[1] + wsum[2] + wsum[3]);
    __syncthreads();

    const float scale = s_scale;
    // 8 contiguous planes = 25088 floats = 6272 float4 per block.
    const size_t fbase = (size_t)blockIdx.x * (PPB * PLANE_OUT / 4);
    const float4* xp = reinterpret_cast<const float4*>(x) + fbase;
    float4* op = reinterpret_cast<float4*>(out) + fbase;

    for (int j = tid; j < PPB * PLANE_OUT / 4; j += 256) {  // ~24.5 iters
        // 14 float4 per row; bitmap word index = j/14 (flattened [8][56]).
        const int wword = j / 14;
        const int q = j - 14 * wword;
        const unsigned m4 = (unsigned)((bitsLDS[wword] >> (4 * q)) & 0xFULL);
        float4 o = {0.f, 0.f, 0.f, 0.f};
        if (m4) {
            float4 v = xp[j];
            o.x = (m4 & 1u) ? v.x * scale : 0.f;
            o.y = (m4 & 2u) ? v.y * scale : 0.f;
            o.z = (m4 & 4u) ? v.z * scale : 0.f;
            o.w = (m4 & 8u) ? v.w * scale : 0.f;
        }
        op[j] = o;
    }
}

extern "C" void kernel_launch(void* const* d_in, const int* in_sizes, int n_in,
                              void* d_out, int out_size, void* d_ws, size_t ws_size,
                              hipStream_t stream)
{
    const float* x    = (const float*)d_in[0];   // (64,256,56,56) f32
    const float* mask = (const float*)d_in[1];   // (64,256,50,50) f32
    float* out = (float*)d_out;

    // d_ws layout:
    //   [0, 64KB)   counts[16384] (u32), fully written by kernel 1
    //   [64KB, ..)  bitmap: 16384*56 u64 = 7.34 MB
    unsigned* counts = (unsigned*)d_ws;
    unsigned long long* bitmap = (unsigned long long*)((char*)d_ws + 65536);

    dropblock_dilate<<<NPLANES, 256, 0, stream>>>(mask, bitmap, counts);
    dropblock_scale<<<K2_BLOCKS, 256, 0, stream>>>(x, bitmap, counts, out);
}

// Round 4
// 118.696 us; speedup vs baseline: 1.0003x; 1.0003x over previous
//
#include <hip/hip_runtime.h>
#include <stdint.h>

#define BS 7
#define HM 50
#define WM 50
#define HH 56
#define WW 56
#define PLANE_IN  (HM * WM)        // 2500
#define PLANE_OUT (HH * WW)        // 3136
#define NPLANES   (64 * 256)       // 16384
#define COUNT_M   51380224.0f     // 64*256*56*56 = 49 * 2^20, exact in fp32
#define PPB       8                // planes per block (both kernels)
#define NBLOCKS   (NPLANES / PPB)  // 2048

typedef unsigned long long u64;

// Kernel 1: 2048 blocks x 8 planes. 7x7 dilation of each 50x50 seed plane ->
// keep bitmaps (bit w of word [plane][h]) + ONE count per block (hierarchical:
// kernel 2 then sums only 2048 u32 = 8KB, not 64KB -- round 3's regression was
// 2048 blocks x 64KB = 134 MB of redundant L2 reads).
__global__ __launch_bounds__(256) void dropblock_dilate(
    const float* __restrict__ mask,
    u64* __restrict__ bitmap,
    unsigned* __restrict__ counts)
{
    __shared__ u64 rowbits[PPB][HM];   // 400 words
    __shared__ u64 rowdil[PPB][HM];
    __shared__ unsigned cnt;

    const int tid = threadIdx.x;
    u64* rb = &rowbits[0][0];
    u64* rd = &rowdil[0][0];

    for (int i = tid; i < PPB * HM; i += 256) rb[i] = 0ULL;
    if (tid == 0) cnt = 0;
    __syncthreads();

    // 8 contiguous planes = 20000 floats = 5000 float4 (2500 % 4 == 0, so no
    // float4 straddles a plane). Sparse seeds (10%) -> LDS atomicOr.
    const float4* mp = reinterpret_cast<const float4*>(
        mask + (size_t)blockIdx.x * (PPB * PLANE_IN));
    for (int j = tid; j < PPB * PLANE_IN / 4; j += 256) {  // 5000
        float4 v = mp[j];
        if (v.x == 0.f && v.y == 0.f && v.z == 0.f && v.w == 0.f) continue;
        const int e = 4 * j;
        const int plane = e / PLANE_IN;
        const int rem = e - plane * PLANE_IN;
        int r = rem / WM;
        int w = rem - r * WM;
        float vv[4] = {v.x, v.y, v.z, v.w};
#pragma unroll
        for (int k = 0; k < 4; ++k) {
            if (vv[k] != 0.f) atomicOr(&rowbits[plane][r], 1ULL << w);
            if (++w == WM) { w = 0; ++r; }   // float4 may straddle a row
        }
    }
    __syncthreads();

    // Row dilation: bit w of s = OR of seed bits [w-6 .. w].
    for (int i = tid; i < PPB * HM; i += 256) {
        u64 b = rb[i];
        u64 s = b | (b << 1);  // shifts 0..1
        s |= s << 2;           // 0..3
        s |= s << 3;           // 0..6
        rd[i] = s;
    }
    __syncthreads();

    // Column dilation + invert + popcount + coalesced bitmap store.
    unsigned pc = 0;
    for (int i = tid; i < PPB * HH; i += 256) {  // 448
        const int plane = i / HH;
        const int h = i - plane * HH;
        int lo = h - (BS - 1); if (lo < 0) lo = 0;
        int hi = h;            if (hi > HM - 1) hi = HM - 1;
        u64 d = 0ULL;
        for (int r = lo; r <= hi; ++r) d |= rowdil[plane][r];
        u64 keep = ~d & ((1ULL << 56) - 1ULL);
        bitmap[(size_t)blockIdx.x * (PPB * HH) + i] = keep;
        pc += (unsigned)__popcll(keep);
    }
    if (pc) atomicAdd(&cnt, pc);  // LDS atomic only
    __syncthreads();
    if (tid == 0) counts[blockIdx.x] = cnt;  // plain store, 1 per block
}

// Kernel 2: fused reduce + scale. 2048 blocks x 8 planes. Per-block count sum
// is now only 8 KB; then stream 6272 contiguous float4 stores per block,
// skipping x loads for all-zero nibbles (~99.4% of pixels dropped).
__global__ __launch_bounds__(256) void dropblock_scale(
    const float* __restrict__ x,
    const u64* __restrict__ bitmap,
    const unsigned* __restrict__ counts,
    float* __restrict__ out)
{
    __shared__ u64 bitsLDS[PPB * HH];  // 448 words
    __shared__ unsigned wsum[4];
    __shared__ float s_scale;

    const int tid = threadIdx.x;

    // Bitmap loads first (they cover the count-sum latency).
    for (int i = tid; i < PPB * HH; i += 256)
        bitsLDS[i] = bitmap[(size_t)blockIdx.x * (PPB * HH) + i];

    // Sum 2048 per-block counts: 2 uint4 per thread.
    const uint4* cp = reinterpret_cast<const uint4*>(counts);
    uint4 a = cp[tid], b = cp[tid + 256];
    unsigned s = a.x + a.y + a.z + a.w + b.x + b.y + b.z + b.w;
#pragma unroll
    for (int off = 32; off; off >>= 1) s += __shfl_down(s, off, 64);
    if ((tid & 63) == 0) wsum[tid >> 6] = s;
    __syncthreads();
    if (tid == 0) s_scale = COUNT_M / (float)(wsum[0] + wsum[1] + wsum[2] + wsum[3]);
    __syncthreads();

    const float scale = s_scale;
    // 8 contiguous planes = 25088 floats = 6272 float4 per block.
    const size_t fbase = (size_t)blockIdx.x * (PPB * PLANE_OUT / 4);
    const float4* xp = reinterpret_cast<const float4*>(x) + fbase;
    float4* op = reinterpret_cast<float4*>(out) + fbase;

    for (int j = tid; j < PPB * PLANE_OUT / 4; j += 256) {
        // 14 float4 per row; bitmap word = j/14 (flattened [8][56] layout).
        const int wword = j / 14;
        const int q = j - 14 * wword;
        const unsigned m4 = (unsigned)((bitsLDS[wword] >> (4 * q)) & 0xFULL);
        float4 o = {0.f, 0.f, 0.f, 0.f};
        if (m4) {
            float4 v = xp[j];
            o.x = (m4 & 1u) ? v.x * scale : 0.f;
            o.y = (m4 & 2u) ? v.y * scale : 0.f;
            o.z = (m4 & 4u) ? v.z * scale : 0.f;
            o.w = (m4 & 8u) ? v.w * scale : 0.f;
        }
        op[j] = o;
    }
}

extern "C" void kernel_launch(void* const* d_in, const int* in_sizes, int n_in,
                              void* d_out, int out_size, void* d_ws, size_t ws_size,
                              hipStream_t stream)
{
    const float* x    = (const float*)d_in[0];   // (64,256,56,56) f32
    const float* mask = (const float*)d_in[1];   // (64,256,50,50) f32
    float* out = (float*)d_out;

    // d_ws layout:
    //   [0, 8KB)    counts[2048] (u32), fully written by kernel 1
    //   [64KB, ..)  bitmap: 2048*448 u64 = 7.34 MB
    unsigned* counts = (unsigned*)d_ws;
    u64* bitmap = (u64*)((char*)d_ws + 65536);

    dropblock_dilate<<<NBLOCKS, 256, 0, stream>>>(mask, bitmap, counts);
    dropblock_scale<<<NBLOCKS, 256, 0, stream>>>(x, bitmap, counts, out);
}